// Round 6
// baseline (395.794 us; speedup 1.0000x reference)
//
#include <hip/hip_runtime.h>
#include <stdint.h>

#define NN 16384
#define FD 128

typedef float f32x4 __attribute__((ext_vector_type(4)));
typedef float f32x16 __attribute__((ext_vector_type(16)));
typedef __bf16 bf16x8 __attribute__((ext_vector_type(8)));
typedef unsigned short u16x8 __attribute__((ext_vector_type(8)));
typedef unsigned short u16x4 __attribute__((ext_vector_type(4)));

static __device__ __forceinline__ unsigned short f2bf(float x) {
  return __builtin_bit_cast(unsigned short, (__bf16)x);
}

static __device__ __forceinline__ u16x8 pack8(f32x4 a, f32x4 b) {
  u16x8 r;
  r[0] = f2bf(a.x); r[1] = f2bf(a.y); r[2] = f2bf(a.z); r[3] = f2bf(a.w);
  r[4] = f2bf(b.x); r[5] = f2bf(b.y); r[6] = f2bf(b.z); r[7] = f2bf(b.w);
  return r;
}

static __device__ __forceinline__ u16x4 pack4(f32x4 a) {
  u16x4 r;
  r[0] = f2bf(a.x); r[1] = f2bf(a.y); r[2] = f2bf(a.z); r[3] = f2bf(a.w);
  return r;
}

// ---------------- kernel 1: norm[i] = (sum_j A[i][j])^-1/2 ----------------
// Plain (cached) loads: the trailing ~256MB of A stays LLC-resident for k3.
__global__ __launch_bounds__(256) void k_rownorm(const float* __restrict__ A,
                                                 float* __restrict__ norm) {
  const int row = blockIdx.x;
  const f32x4* ar = (const f32x4*)(A + (size_t)row * NN);
  float s = 0.f;
#pragma unroll 4
  for (int c = threadIdx.x; c < NN / 4; c += 256) {
    f32x4 v = ar[c];
    s += (v.x + v.y) + (v.z + v.w);
  }
#pragma unroll
  for (int off = 32; off > 0; off >>= 1) s += __shfl_xor(s, off, 64);
  __shared__ float red[4];
  const int lane = threadIdx.x & 63, w = threadIdx.x >> 6;
  if (lane == 0) red[w] = s;
  __syncthreads();
  if (threadIdx.x == 0) {
    float d = (red[0] + red[1]) + (red[2] + red[3]);
    norm[row] = d > 0.f ? 1.f / sqrtf(d) : 0.f;
  }
}

// ------- kernel 2: Bfrag = fragment-major bf16( norm[j] * (F @ W^T)[j][o] ) -------
// Bfrag layout: entry (t = j>>4, c = o>>5, lane l, e) at byte ((t*4+c)*64 + l)*16 + e*2
// holds norm[j]*H[j][o] with o = c*32 + (l&31), j = t*16 + (l>>5)*8 + e.
__global__ __launch_bounds__(256) void k_fwt(const float* __restrict__ F,
                                             const float* __restrict__ W,
                                             const float* __restrict__ norm,
                                             unsigned short* __restrict__ Bfrag) {
  const int tid = threadIdx.x;
  const int wv = tid >> 6;
  const int l = tid & 63;
  const int lr = l & 31, lg = l >> 5;
  const int j0 = blockIdx.x * 32;

  const float* fp = F + (size_t)(j0 + lr) * FD + lg * 8;
  const float* wp = W + (size_t)(wv * 32 + lr) * FD + lg * 8;

  f32x16 acc;
#pragma unroll
  for (int i = 0; i < 16; ++i) acc[i] = 0.f;

#pragma unroll
  for (int kf = 0; kf < 8; ++kf) {
    f32x4 fa = *(const f32x4*)(fp + kf * 16);
    f32x4 fb = *(const f32x4*)(fp + kf * 16 + 4);
    f32x4 wa = *(const f32x4*)(wp + kf * 16);
    f32x4 wb = *(const f32x4*)(wp + kf * 16 + 4);
    bf16x8 av = __builtin_bit_cast(bf16x8, pack8(fa, fb));
    bf16x8 bv = __builtin_bit_cast(bf16x8, pack8(wa, wb));
    acc = __builtin_amdgcn_mfma_f32_32x32x16_bf16(av, bv, acc, 0, 0, 0);
  }

  const int jt = blockIdx.x * 2;  // j0 >> 4
#pragma unroll
  for (int g = 0; g < 4; ++g) {
    const int jb = j0 + g * 8 + lg * 4;
    u16x4 q;
#pragma unroll
    for (int r2 = 0; r2 < 4; ++r2) q[r2] = f2bf(acc[g * 4 + r2] * norm[jb + r2]);
    const size_t byteoff =
        ((size_t)((jt + (g >> 1)) * 4 + wv) * 64 + (g & 1) * 32 + lr) * 16 +
        lg * 8;
    *(u16x4*)((char*)Bfrag + byteoff) = q;
  }
}

// ---------- kernel 3: out[i][o] = norm[i] * sum_j A[i][j]*(norm[j]*H[j][o]) + b[o] ----------
// BM=64, BK=256. 256 blocks x 1024 thr (16 waves = 4 col x 2 m-sub x 2 k-groups).
// A: wave-contiguous full-line loads (R5 fix) + 2-DEEP register pipeline: loads for
// tile s+2 issue at step s (regA/regB alternate); LDS write consumes loads issued a
// full step earlier. K-loop barrier = lgkmcnt(0) + raw s_barrier + sched_barrier(0)
// (vmcnt never drained -> A loads live across barriers, T3/T4 pattern).
// B: fragment-major bf16 from L2/LLC, coalesced 1KB/wave dwordx4 -> regs.
// K-split (kg) reduced via LDS in epilogue; coalesced f32x4 out stores.
__global__ __launch_bounds__(1024, 4) void k_gcn_gemm(
    const float* __restrict__ A, const unsigned short* __restrict__ Bfrag,
    const float* __restrict__ norm, const float* __restrict__ bias,
    float* __restrict__ out) {
  __shared__ __align__(16) unsigned short Alds[2][64 * 256];  // 2 x 32 KB

  const int tid = threadIdx.x;
  const int i0 = blockIdx.x * 64;

  // A staging: wave w = srow, lane sl; load i covers row i*16+srow
  const int srow = tid >> 6;   // 0..15
  const int sl = tid & 63;
  const float* aptr = A + (size_t)(i0 + srow) * NN + (size_t)sl * 4;
  const unsigned abase =
      (unsigned)(srow * 512) + ((unsigned)(sl * 8) ^ (unsigned)(srow << 4));

  // fragment addressing
  const int wv = tid >> 6;          // 0..15
  const int c = wv & 3;             // col-group: o in [c*32, c*32+32)
  const int m = (wv >> 2) & 1;      // m-subtile: rows m*32..m*32+31
  const int kg = wv >> 3;           // k-half within BK=256
  const int l = tid & 63;
  const int lr = l & 31, lg = l >> 5;
  const int rowl = m * 32 + lr;
  const unsigned swz = (unsigned)((rowl & 15) << 4);
  const unsigned arb = (unsigned)(rowl * 512);
  const unsigned kgb = (unsigned)(kg * 256);  // kg*128 elements, bytes

  const char* bptr = (const char*)Bfrag + (size_t)(c * 64 + l) * 16 +
                     (size_t)kg * 8 * 4096;

  f32x16 acc;
#pragma unroll
  for (int i = 0; i < 16; ++i) acc[i] = 0.f;

  f32x4 a0, a1, a2, a3, b0, b1, b2, b3;

#define ALOAD(RV, S, I)                                                     \
  RV = __builtin_nontemporal_load(                                          \
      (const f32x4*)(aptr + (size_t)(S) * 256 + (size_t)(I) * (16 * NN)));
#define AWRITE(BUF, RV, I)                                                  \
  *(u16x4*)((char*)Alds[BUF] + (abase + (I) * 8192)) = pack4(RV);
#define BARR                                                                \
  do {                                                                      \
    asm volatile("s_waitcnt lgkmcnt(0)" ::: "memory");                      \
    __builtin_amdgcn_s_barrier();                                           \
    __builtin_amdgcn_sched_barrier(0);                                      \
  } while (0)
#define MFMA_BLOCK(CUR, S)                                                  \
  {                                                                         \
    const char* bp_ = bptr + (size_t)(S) * (16 * 4096);                     \
    _Pragma("unroll") for (int kf = 0; kf < 8; ++kf) {                      \
      u16x8 bv = *(const u16x8*)(bp_ + (size_t)kf * 4096);                  \
      unsigned ko = (kgb + (unsigned)(kf * 32) + (unsigned)(lg * 16)) ^ swz;\
      u16x8 av = *(const u16x8*)((const char*)Alds[CUR] + (arb + ko));      \
      acc = __builtin_amdgcn_mfma_f32_32x32x16_bf16(                        \
          __builtin_bit_cast(bf16x8, av), __builtin_bit_cast(bf16x8, bv),   \
          acc, 0, 0, 0);                                                    \
    }                                                                       \
  }

  // prologue: tile0 -> regA -> buf0; tile1 -> regB (in flight)
  ALOAD(a0, 0, 0) ALOAD(a1, 0, 1) ALOAD(a2, 0, 2) ALOAD(a3, 0, 3)
  ALOAD(b0, 1, 0) ALOAD(b1, 1, 1) ALOAD(b2, 1, 2) ALOAD(b3, 1, 3)
  AWRITE(0, a0, 0) AWRITE(0, a1, 1) AWRITE(0, a2, 2) AWRITE(0, a3, 3)
  BARR;

#pragma unroll 1
  for (int s = 0; s < 64; s += 2) {
    // even step: compute buf0(tile s); write regB(tile s+1)->buf1; load regA<-tile s+2
    {
      if (s + 2 < 64) {
        ALOAD(a0, s + 2, 0) ALOAD(a1, s + 2, 1)
        ALOAD(a2, s + 2, 2) ALOAD(a3, s + 2, 3)
      }
      MFMA_BLOCK(0, s)
      AWRITE(1, b0, 0) AWRITE(1, b1, 1) AWRITE(1, b2, 2) AWRITE(1, b3, 3)
      BARR;
    }
    // odd step: compute buf1(tile s+1); write regA(tile s+2)->buf0; load regB<-tile s+3
    {
      if (s + 3 < 64) {
        ALOAD(b0, s + 3, 0) ALOAD(b1, s + 3, 1)
        ALOAD(b2, s + 3, 2) ALOAD(b3, s + 3, 3)
      }
      MFMA_BLOCK(1, s + 1)
      if (s + 2 < 64) {
        AWRITE(0, a0, 0) AWRITE(0, a1, 1) AWRITE(0, a2, 2) AWRITE(0, a3, 3)
      }
      BARR;
    }
  }
#undef MFMA_BLOCK
#undef BARR
#undef ALOAD
#undef AWRITE

  // ---- epilogue: reduce kg halves via LDS, then coalesced store ----
  // D: col(o-local) = c*32 + lr, row(i-local) = m*32 + g*8 + lg*4 + r2
  float* red = (float*)Alds;  // 64x128 f32 = 32 KB (final loop barrier passed)
  if (kg == 1) {
#pragma unroll
    for (int g = 0; g < 4; ++g) {
      const int jb = m * 32 + g * 8 + lg * 4;
#pragma unroll
      for (int r2 = 0; r2 < 4; ++r2)
        red[(jb + r2) * 128 + c * 32 + lr] = acc[g * 4 + r2];
    }
  }
  __syncthreads();
  if (kg == 0) {
#pragma unroll
    for (int g = 0; g < 4; ++g) {
      const int jb = m * 32 + g * 8 + lg * 4;
#pragma unroll
      for (int r2 = 0; r2 < 4; ++r2)
        red[(jb + r2) * 128 + c * 32 + lr] += acc[g * 4 + r2];
    }
  }
  __syncthreads();

  {
    const int row = tid >> 4;            // 0..63
    const int colseg = (tid & 15) * 8;   // 0..120
    const float nm = norm[i0 + row];
    f32x4 v0 = *(const f32x4*)(red + row * 128 + colseg);
    f32x4 v1 = *(const f32x4*)(red + row * 128 + colseg + 4);
    f32x4 b0v = *(const f32x4*)(bias + colseg);
    f32x4 b1v = *(const f32x4*)(bias + colseg + 4);
    f32x4 o0, o1;
    o0.x = nm * v0.x + b0v.x; o0.y = nm * v0.y + b0v.y;
    o0.z = nm * v0.z + b0v.z; o0.w = nm * v0.w + b0v.w;
    o1.x = nm * v1.x + b1v.x; o1.y = nm * v1.y + b1v.y;
    o1.z = nm * v1.z + b1v.z; o1.w = nm * v1.w + b1v.w;
    float* op = out + (size_t)(i0 + row) * FD + colseg;
    *(f32x4*)op = o0;
    *(f32x4*)(op + 4) = o1;
  }
}

extern "C" void kernel_launch(void* const* d_in, const int* in_sizes, int n_in,
                              void* d_out, int out_size, void* d_ws,
                              size_t ws_size, hipStream_t stream) {
  (void)in_sizes; (void)n_in; (void)out_size; (void)ws_size;
  const float* A = (const float*)d_in[0];
  const float* F = (const float*)d_in[1];
  const float* W = (const float*)d_in[2];
  const float* b = (const float*)d_in[3];
  float* out = (float*)d_out;

  float* norm = (float*)d_ws;                                     // 64 KB
  unsigned short* Bfrag = (unsigned short*)((char*)d_ws + 65536); // 4 MB

  k_rownorm<<<NN, 256, 0, stream>>>(A, norm);
  k_fwt<<<NN / 32, 256, 0, stream>>>(F, W, norm, Bfrag);
  k_gcn_gemm<<<NN / 64, 1024, 0, stream>>>(A, Bfrag, norm, b, out);
}